// Round 2
// baseline (644.697 us; speedup 1.0000x reference)
//
#include <hip/hip_runtime.h>
#include <math.h>

#define TT 8
#define NTOK 12288
#define DD 256
#define NNODE 8192
#define NNODES 32768
#define CLEN 16
#define CDIM 64
#define CHUNK 2048
#define H1 128
#define NBUCK 256      // buckets per t (node>>7)
#define GCAP 256       // rowbuf capacity per bucket (global)
#define LCAP 64        // rows staged in LDS per bucket

__device__ __forceinline__ float gelu_exact(float v) {
    return 0.5f * v * (1.0f + erff(v * 0.70710678118654752f));
}

// ---- Kernel 1: LN(x) + GEMM (xn @ w1, 256->128) -> y dense; fused bucket fill ----
// grid (128 rowblocks, 8 t), block 256. Each block: 64 rows x 128 cols.
__global__ __launch_bounds__(256) void k_ln_gemm(
    const float* __restrict__ x, const int* __restrict__ indices,
    const float* __restrict__ ln1_g, const float* __restrict__ ln1_b,
    const float* __restrict__ w1, float* __restrict__ y,
    int* __restrict__ cur, int* __restrict__ rowbuf)
{
    const int t = blockIdx.y;
    const int rowBase = blockIdx.x * 64;
    const int tid = threadIdx.x;

    __shared__ float As[64][36];
    __shared__ float Bs[32][128];
    __shared__ float red[64][4][2];
    __shared__ float mS[64], rS[64];

    const float* xblk = x + ((size_t)t * NTOK + rowBase) * DD;

    // bucket fill (independent of GEMM): 64 threads, one row each
    if (tid < 64) {
        const int i = rowBase + tid;
        const int node = indices[t * NNODE + i];
        const int b = node >> 7;
        const int pos = atomicAdd(&cur[t * NBUCK + b], 1);
        if (pos < GCAP)
            rowbuf[((t * NBUCK + b) << 8) + pos] = (i << 8) | (node & 127);
    }

    // LN stats per row (4 threads/row)
    {
        const int row = tid >> 2, q = tid & 3;
        const float* xr = xblk + (size_t)row * DD;
        float s = 0.f, ss = 0.f;
        #pragma unroll
        for (int u = 0; u < 16; ++u) {
            const float4 v = *(const float4*)(xr + (u * 4 + q) * 4);
            s  += v.x + v.y + v.z + v.w;
            ss += v.x*v.x + v.y*v.y + v.z*v.z + v.w*v.w;
        }
        red[row][q][0] = s;
        red[row][q][1] = ss;
    }
    __syncthreads();
    if (tid < 64) {
        const float s  = red[tid][0][0] + red[tid][1][0] + red[tid][2][0] + red[tid][3][0];
        const float ss = red[tid][0][1] + red[tid][1][1] + red[tid][2][1] + red[tid][3][1];
        const float m = s * (1.0f / 256.0f);
        const float var = ss * (1.0f / 256.0f) - m * m;
        mS[tid] = m;
        rS[tid] = rsqrtf(var + 1e-5f);
    }
    __syncthreads();

    const int ty = tid >> 4;   // rows ty*4 .. ty*4+3
    const int tx = tid & 15;   // cols tx*8 .. tx*8+7
    float acc[4][8];
    #pragma unroll
    for (int j = 0; j < 4; ++j)
        #pragma unroll
        for (int jj = 0; jj < 8; ++jj) acc[j][jj] = 0.f;

    for (int kt = 0; kt < 8; ++kt) {
        #pragma unroll
        for (int u = 0; u < 2; ++u) {
            const int f = tid + u * 256;
            const int row = f >> 3, c4 = f & 7;
            const int k0 = kt * 32 + c4 * 4;
            float4 v = *(const float4*)(xblk + (size_t)row * DD + k0);
            const float4 g = *(const float4*)(ln1_g + k0);
            const float4 b = *(const float4*)(ln1_b + k0);
            const float m = mS[row], r = rS[row];
            v.x = (v.x - m) * r * g.x + b.x;
            v.y = (v.y - m) * r * g.y + b.y;
            v.z = (v.z - m) * r * g.z + b.z;
            v.w = (v.w - m) * r * g.w + b.w;
            *(float4*)&As[row][c4 * 4] = v;
        }
        #pragma unroll
        for (int u = 0; u < 4; ++u) {
            const int f = tid + u * 256;
            const int row = f >> 5, c4 = f & 31;
            *(float4*)&Bs[row][c4 * 4] =
                *(const float4*)(w1 + (size_t)(kt * 32 + row) * H1 + c4 * 4);
        }
        __syncthreads();
        #pragma unroll
        for (int k = 0; k < 32; ++k) {
            const float a0 = As[ty*4+0][k];
            const float a1r = As[ty*4+1][k];
            const float a2 = As[ty*4+2][k];
            const float a3 = As[ty*4+3][k];
            const float4 b0 = *(const float4*)&Bs[k][tx*8];
            const float4 b4 = *(const float4*)&Bs[k][tx*8+4];
#define ACC_ROW(J, AJ) \
            acc[J][0] += AJ*b0.x; acc[J][1] += AJ*b0.y; acc[J][2] += AJ*b0.z; acc[J][3] += AJ*b0.w; \
            acc[J][4] += AJ*b4.x; acc[J][5] += AJ*b4.y; acc[J][6] += AJ*b4.z; acc[J][7] += AJ*b4.w;
            ACC_ROW(0, a0) ACC_ROW(1, a1r) ACC_ROW(2, a2) ACC_ROW(3, a3)
#undef ACC_ROW
        }
        __syncthreads();
    }

    // plain stores to dense y[t, row, 128]
    #pragma unroll
    for (int j = 0; j < 4; ++j) {
        const int i = rowBase + ty * 4 + j;
        float* dst = y + (((size_t)t * NNODE + i) << 7) + tx * 8;
        *(float4*)dst = make_float4(acc[j][0], acc[j][1], acc[j][2], acc[j][3]);
        *(float4*)(dst + 4) = make_float4(acc[j][4], acc[j][5], acc[j][6], acc[j][7]);
    }
}

// ---- Kernel 2: per-bucket node sums: sbuf[t,l,c] += sum over 128 nodes of gelu(b1+sum y) ----
// grid (sub 16, l 16, t 8), block 256 = 2 node-halves x 128 cols
__global__ __launch_bounds__(256) void k_node_sum(
    const float* __restrict__ y, const float* __restrict__ b1,
    const int* __restrict__ cur, const int* __restrict__ rowbuf,
    float* __restrict__ sbuf)
{
    const int tid = threadIdx.x;
    const int sub = blockIdx.x, l = blockIdx.y, t = blockIdx.z;
    const int b = l * 16 + sub;                // bucket id within t
    const int bg = t * NBUCK + b;

    __shared__ int   meta[GCAP];
    __shared__ float ybuf[LCAP][H1];
    __shared__ float redc[256];

    int nrows = cur[bg];
    if (nrows > GCAP) nrows = GCAP;
    const int nA = nrows < LCAP ? nrows : LCAP;

    if (tid < nrows) meta[tid] = rowbuf[(bg << 8) + tid];
    __syncthreads();

    // stage first nA rows of y into LDS
    for (int e = tid; e < nA * H1; e += 256) {
        const int r = e >> 7, c = e & 127;
        const int row = meta[r] >> 8;
        ybuf[r][c] = y[(((size_t)t * NNODE + row) << 7) + c];
    }
    __syncthreads();

    const int h = tid >> 7;        // node half
    const int c = tid & 127;       // column
    const float b1c = b1[c];
    float cs = 0.f;

    for (int p = 0; p < 64; ++p) {
        const int nl = p * 2 + h;  // node-local id 0..127
        float acc = b1c;
        for (int r = 0; r < nA; ++r) {
            if ((meta[r] & 255) == nl) acc += ybuf[r][c];
        }
        for (int r = nA; r < nrows; ++r) {   // cold overflow path
            const int m = meta[r];
            if ((m & 255) == nl)
                acc += y[(((size_t)t * NNODE + (m >> 8)) << 7) + c];
        }
        cs += gelu_exact(acc);
    }

    redc[tid] = cs;
    __syncthreads();
    if (tid < 128)
        atomicAdd(&sbuf[(t * CLEN + l) * H1 + c], redc[tid] + redc[tid + 128]);
}

// ---- Kernel 3: comp = sbuf @ w2 + 2048*b2 ; lnf ; lnd ; decoder MLP -> decRow[t,16,256] ----
__global__ __launch_bounds__(256) void k_decode(
    const float* __restrict__ sbuf, const float* __restrict__ w2,
    const float* __restrict__ b2,
    const float* __restrict__ lnf_g, const float* __restrict__ lnf_b,
    const float* __restrict__ lnd_g, const float* __restrict__ lnd_b,
    const float* __restrict__ dw1, const float* __restrict__ db1,
    const float* __restrict__ dw2, const float* __restrict__ db2,
    float* __restrict__ decRow)
{
    const int t = blockIdx.x, tid = threadIdx.x;
    __shared__ float comp[CLEN * CDIM];
    __shared__ float2 red2[256];
    __shared__ float vv[CLEN][CDIM];
    __shared__ float hh[CLEN][H1];
    __shared__ float mvS[2];
    __shared__ float m2S[CLEN], r2S[CLEN];

    #pragma unroll
    for (int u = 0; u < 4; ++u) {
        const int j = tid + u * 256;
        const int l = j >> 6, cc = j & 63;
        const float* sp = sbuf + (t * CLEN + l) * H1;
        float a = (float)CHUNK * b2[cc];
        for (int k = 0; k < H1; ++k) a += sp[k] * w2[k * CDIM + cc];
        comp[j] = a;
    }
    __syncthreads();
    {
        float s = 0.f, ss = 0.f;
        #pragma unroll
        for (int u = 0; u < 4; ++u) { const float v = comp[tid + u * 256]; s += v; ss += v * v; }
        red2[tid] = make_float2(s, ss);
        __syncthreads();
        for (int st = 128; st > 0; st >>= 1) {
            if (tid < st) {
                red2[tid].x += red2[tid + st].x;
                red2[tid].y += red2[tid + st].y;
            }
            __syncthreads();
        }
        if (tid == 0) {
            const float m = red2[0].x * (1.0f / 1024.0f);
            const float var = red2[0].y * (1.0f / 1024.0f) - m * m;
            mvS[0] = m; mvS[1] = rsqrtf(var + 1e-5f);
        }
        __syncthreads();
        const float m = mvS[0], r = mvS[1];
        #pragma unroll
        for (int u = 0; u < 4; ++u) {
            const int j = tid + u * 256;
            comp[j] = (comp[j] - m) * r * lnf_g[j] + lnf_b[j];
        }
    }
    __syncthreads();
    {
        const int l = tid >> 4, q = tid & 15;
        float s = 0.f, ss = 0.f;
        #pragma unroll
        for (int e = 0; e < 4; ++e) {
            const float v = comp[l * CDIM + q * 4 + e];
            s += v; ss += v * v;
        }
        red2[tid] = make_float2(s, ss);
        __syncthreads();
        if (tid < CLEN) {
            float sa = 0.f, sb = 0.f;
            for (int k = 0; k < 16; ++k) { sa += red2[tid * 16 + k].x; sb += red2[tid * 16 + k].y; }
            const float m = sa * (1.0f / 64.0f);
            const float var = sb * (1.0f / 64.0f) - m * m;
            m2S[tid] = m; r2S[tid] = rsqrtf(var + 1e-5f);
        }
        __syncthreads();
        #pragma unroll
        for (int u = 0; u < 4; ++u) {
            const int j = tid + u * 256;
            const int l2 = j >> 6, cc = j & 63;
            vv[l2][cc] = (comp[j] - m2S[l2]) * r2S[l2] * lnd_g[cc] + lnd_b[cc];
        }
    }
    __syncthreads();
    #pragma unroll
    for (int u = 0; u < 8; ++u) {
        const int j = tid + u * 256;
        const int l = j >> 7, cc = j & 127;
        float a = db1[cc];
        for (int k = 0; k < CDIM; ++k) a += vv[l][k] * dw1[k * H1 + cc];
        hh[l][cc] = gelu_exact(a);
    }
    __syncthreads();
    #pragma unroll
    for (int u = 0; u < 16; ++u) {
        const int j = tid + u * 256;
        const int l = j >> 8, cc = j & 255;
        float a = db2[cc];
        for (int k = 0; k < H1; ++k) a += hh[l][k] * dw2[k * DD + cc];
        decRow[(t * CLEN + l) * DD + cc] = a;
    }
}

// ---- Kernel 4: out[t,i,:] = decRow[t, idx[t,i]>>11, :] for i<8192 else 0 ----
__global__ __launch_bounds__(256) void k_gather(
    const int* __restrict__ indices, const float* __restrict__ decRow,
    float* __restrict__ out)
{
    const int tid = threadIdx.x;
    const int r = blockIdx.x * 4 + (tid >> 6);
    const int c4 = tid & 63;
    const int t = r / NTOK;
    const int i = r - t * NTOK;
    float4 v = make_float4(0.f, 0.f, 0.f, 0.f);
    if (i < NNODE) {
        const int node = indices[t * NNODE + i];
        const int l = node >> 11;
        v = *(const float4*)(decRow + (t * CLEN + l) * DD + c4 * 4);
    }
    *(float4*)(out + (size_t)r * DD + c4 * 4) = v;
}

extern "C" void kernel_launch(void* const* d_in, const int* in_sizes, int n_in,
                              void* d_out, int out_size, void* d_ws, size_t ws_size,
                              hipStream_t stream)
{
    const float* x       = (const float*)d_in[0];
    const int*   indices = (const int*)d_in[1];
    const float* ln1_g   = (const float*)d_in[2];
    const float* ln1_b   = (const float*)d_in[3];
    const float* w1      = (const float*)d_in[4];
    const float* b1      = (const float*)d_in[5];
    const float* w2      = (const float*)d_in[6];
    const float* b2      = (const float*)d_in[7];
    const float* lnf_g   = (const float*)d_in[8];
    const float* lnf_b   = (const float*)d_in[9];
    const float* lnd_g   = (const float*)d_in[10];
    const float* lnd_b   = (const float*)d_in[11];
    const float* dw1     = (const float*)d_in[12];
    const float* db1     = (const float*)d_in[13];
    const float* dw2     = (const float*)d_in[14];
    const float* db2     = (const float*)d_in[15];
    float* out = (float*)d_out;

    char* ws = (char*)d_ws;
    int*   cur    = (int*)ws;                          // 8*256*4      = 8 KiB
    float* sbuf   = (float*)(ws + 8192);               // 8*16*128*4   = 64 KiB
    int*   rowbuf = (int*)(ws + 73728);                // 8*256*256*4  = 2 MiB
    float* decRow = (float*)(ws + 2170880);            // 8*16*256*4   = 128 KiB
    float* y      = (float*)(ws + 2301952);            // 8*8192*128*4 = 32 MiB

    hipMemsetAsync(ws, 0, 73728, stream);              // cur + sbuf

    k_ln_gemm<<<dim3(128, 8), 256, 0, stream>>>(x, indices, ln1_g, ln1_b, w1, y, cur, rowbuf);
    k_node_sum<<<dim3(16, 16, 8), 256, 0, stream>>>(y, b1, cur, rowbuf, sbuf);
    k_decode<<<8, 256, 0, stream>>>(sbuf, w2, b2, lnf_g, lnf_b, lnd_g, lnd_b,
                                    dw1, db1, dw2, db2, decRow);
    k_gather<<<24576, 256, 0, stream>>>(indices, decRow, out);
}

// Round 3
// 322.124 us; speedup vs baseline: 2.0014x; 2.0014x over previous
//
#include <hip/hip_runtime.h>
#include <math.h>

#define TT 8
#define NTOK 12288
#define DD 256
#define NNODE 8192
#define NNODES 32768
#define CLEN 16
#define CDIM 64
#define CHUNK 2048
#define H1 128

__device__ __forceinline__ float gelu_exact(float v) {
    return 0.5f * v * (1.0f + erff(v * 0.70710678118654752f));
}

// ---- Kernel 1: LN(x) + GEMM (xn @ w1, 256->128) -> y dense; record rows per node ----
// grid (128 rowblocks, 8 t), block 256. Each block: 64 rows x 128 cols.
__global__ __launch_bounds__(256) void k_ln_gemm(
    const float* __restrict__ x, const int* __restrict__ indices,
    const float* __restrict__ ln1_g, const float* __restrict__ ln1_b,
    const float* __restrict__ w1, float* __restrict__ y,
    int* __restrict__ cnt, int* __restrict__ slot0, int* __restrict__ slotsx,
    int* __restrict__ ovfcnt, int* __restrict__ ovf)
{
    const int t = blockIdx.y;
    const int rowBase = blockIdx.x * 64;
    const int tid = threadIdx.x;

    __shared__ float As[32 * 68];      // [k][row], stride 68
    __shared__ float Bs[32 * 132];     // [k][col], stride 132
    __shared__ float red[64][4][2];
    __shared__ float mS[64], rS[64];

    const float* xblk = x + ((size_t)t * NTOK + rowBase) * DD;

    // per-node row recording (64 rows of this block)
    if (tid < 64) {
        const int i = rowBase + tid;
        const int node = indices[t * NNODE + i];
        const int g = t * NNODES + node;
        const int pos = atomicAdd(&cnt[g], 1);
        if (pos == 0) slot0[g] = i;
        else if (pos <= 15) slotsx[(size_t)g * 15 + (pos - 1)] = i;
        else {
            const int op = atomicAdd(&ovfcnt[t], 1);
            ovf[t * NNODE + op] = (node << 13) | i;
        }
    }

    // LN stats per row (4 threads/row)
    {
        const int row = tid >> 2, q = tid & 3;
        const float* xr = xblk + (size_t)row * DD;
        float s = 0.f, ss = 0.f;
        #pragma unroll
        for (int u = 0; u < 16; ++u) {
            const float4 v = *(const float4*)(xr + (u * 4 + q) * 4);
            s  += v.x + v.y + v.z + v.w;
            ss += v.x*v.x + v.y*v.y + v.z*v.z + v.w*v.w;
        }
        red[row][q][0] = s;
        red[row][q][1] = ss;
    }
    __syncthreads();
    if (tid < 64) {
        const float s  = red[tid][0][0] + red[tid][1][0] + red[tid][2][0] + red[tid][3][0];
        const float ss = red[tid][0][1] + red[tid][1][1] + red[tid][2][1] + red[tid][3][1];
        const float m = s * (1.0f / 256.0f);
        const float var = ss * (1.0f / 256.0f) - m * m;
        mS[tid] = m;
        rS[tid] = rsqrtf(var + 1e-5f);
    }
    __syncthreads();

    const int ty = tid >> 4;   // rows ty*4 .. ty*4+3
    const int tx = tid & 15;   // cols tx*8 .. tx*8+7
    float acc[4][8];
    #pragma unroll
    for (int j = 0; j < 4; ++j)
        #pragma unroll
        for (int jj = 0; jj < 8; ++jj) acc[j][jj] = 0.f;

    for (int kt = 0; kt < 8; ++kt) {
        // stage A tile transposed: As[k][row]
        #pragma unroll
        for (int u = 0; u < 2; ++u) {
            const int f = tid + u * 256;
            const int row = f >> 3, c4 = f & 7;
            const int k0 = kt * 32 + c4 * 4;
            float4 v = *(const float4*)(xblk + (size_t)row * DD + k0);
            const float4 g = *(const float4*)(ln1_g + k0);
            const float4 b = *(const float4*)(ln1_b + k0);
            const float m = mS[row], r = rS[row];
            As[(c4 * 4 + 0) * 68 + row] = (v.x - m) * r * g.x + b.x;
            As[(c4 * 4 + 1) * 68 + row] = (v.y - m) * r * g.y + b.y;
            As[(c4 * 4 + 2) * 68 + row] = (v.z - m) * r * g.z + b.z;
            As[(c4 * 4 + 3) * 68 + row] = (v.w - m) * r * g.w + b.w;
        }
        // stage B tile: Bs[k][col]
        #pragma unroll
        for (int u = 0; u < 4; ++u) {
            const int f = tid + u * 256;
            const int row = f >> 5, c4 = f & 31;
            *(float4*)&Bs[row * 132 + c4 * 4] =
                *(const float4*)(w1 + (size_t)(kt * 32 + row) * H1 + c4 * 4);
        }
        __syncthreads();
        #pragma unroll
        for (int k = 0; k < 32; ++k) {
            const float4 a  = *(const float4*)&As[k * 68 + ty * 4];
            const float4 b0 = *(const float4*)&Bs[k * 132 + tx * 8];
            const float4 b4 = *(const float4*)&Bs[k * 132 + tx * 8 + 4];
#define ACC_ROW(J, AJ) \
            acc[J][0] += AJ*b0.x; acc[J][1] += AJ*b0.y; acc[J][2] += AJ*b0.z; acc[J][3] += AJ*b0.w; \
            acc[J][4] += AJ*b4.x; acc[J][5] += AJ*b4.y; acc[J][6] += AJ*b4.z; acc[J][7] += AJ*b4.w;
            ACC_ROW(0, a.x) ACC_ROW(1, a.y) ACC_ROW(2, a.z) ACC_ROW(3, a.w)
#undef ACC_ROW
        }
        __syncthreads();
    }

    #pragma unroll
    for (int j = 0; j < 4; ++j) {
        const int i = rowBase + ty * 4 + j;
        float* dst = y + (((size_t)t * NNODE + i) << 7) + tx * 8;
        *(float4*)dst = make_float4(acc[j][0], acc[j][1], acc[j][2], acc[j][3]);
        *(float4*)(dst + 4) = make_float4(acc[j][4], acc[j][5], acc[j][6], acc[j][7]);
    }
}

// ---- Kernel 2: per-node sums -> gelu -> chunk sum into sbuf ----
// grid (sub 8, l 16, t 8), block 256 = 2 node-lanes x 128 cols. 256 nodes/block.
__global__ __launch_bounds__(256) void k_node_sum(
    const float* __restrict__ y, const float* __restrict__ b1,
    const int* __restrict__ cnt, const int* __restrict__ slot0,
    const int* __restrict__ slotsx,
    const int* __restrict__ ovfcnt, const int* __restrict__ ovf,
    float* __restrict__ sbuf)
{
    const int tid = threadIdx.x;
    const int sub = blockIdx.x, l = blockIdx.y, t = blockIdx.z;
    const int base = l * CHUNK + sub * 256;      // first node of this block

    __shared__ int cS[256], s0S[256];
    __shared__ float redc[256];

    cS[tid]  = cnt[t * NNODES + base + tid];
    s0S[tid] = slot0[t * NNODES + base + tid];
    __syncthreads();

    const int c = tid & 127;     // column
    const int h = tid >> 7;      // node parity
    const float b1c = b1[c];
    const float geluB = gelu_exact(b1c);
    const float* ybase = y + (((size_t)t * NNODE) << 7) + c;

    float cs = 0.f;
    int zc = 0;

    for (int p = 0; p < 128; ++p) {
        const int nl = p * 2 + h;          // node-local 0..255 (uniform per wave)
        const int n = cS[nl];
        if (n == 0) { ++zc; continue; }
        float acc = b1c + ybase[(size_t)s0S[nl] << 7];
        if (n > 1) {
            const int m = n < 16 ? n : 16;
            const int* sx = slotsx + (size_t)(t * NNODES + base + nl) * 15;
            for (int j = 0; j < m - 1; ++j)
                acc += ybase[(size_t)sx[j] << 7];
            if (n > 16) {                   // ultra-rare overflow path
                int oc = ovfcnt[t]; if (oc > NNODE) oc = NNODE;
                const int node = base + nl;
                for (int e = 0; e < oc; ++e) {
                    const int v = ovf[t * NNODE + e];
                    if ((v >> 13) == node) acc += ybase[(size_t)(v & 8191) << 7];
                }
            }
        }
        cs += gelu_exact(acc);
    }
    cs += (float)zc * geluB;

    redc[tid] = cs;
    __syncthreads();
    if (tid < 128)
        atomicAdd(&sbuf[(t * CLEN + l) * H1 + c], redc[tid] + redc[tid + 128]);
}

// ---- Kernel 3: comp = sbuf @ w2 + 2048*b2 ; lnf ; lnd ; decoder MLP -> decRow ----
// grid 8 (per t), block 256. All weights staged through LDS.
__global__ __launch_bounds__(256) void k_decode(
    const float* __restrict__ sbuf, const float* __restrict__ w2,
    const float* __restrict__ b2,
    const float* __restrict__ lnf_g, const float* __restrict__ lnf_b,
    const float* __restrict__ lnd_g, const float* __restrict__ lnd_b,
    const float* __restrict__ dw1, const float* __restrict__ db1,
    const float* __restrict__ dw2, const float* __restrict__ db2,
    float* __restrict__ decRow)
{
    const int t = blockIdx.x, tid = threadIdx.x;
    __shared__ float wbuf[8192];          // staged weight chunk (32 KiB)
    __shared__ float sb[CLEN * H1];       // staged sbuf[t] (8 KiB)
    __shared__ float comp[CLEN * CDIM];
    __shared__ float2 red2[256];
    __shared__ float vv[CLEN][CDIM];
    __shared__ float hh[CLEN][H1];
    __shared__ float mvS[2];
    __shared__ float m2S[CLEN], r2S[CLEN];

    // stage sbuf + w2 (128x64)
    #pragma unroll
    for (int u = 0; u < 2; ++u) {
        const int j4 = (tid + u * 256) * 4;
        if (j4 < CLEN * H1) *(float4*)&sb[j4] = *(const float4*)(sbuf + t * CLEN * H1 + j4);
    }
    #pragma unroll
    for (int u = 0; u < 8; ++u) {
        const int j4 = (tid + u * 256) * 4;
        *(float4*)&wbuf[j4] = *(const float4*)(w2 + j4);
    }
    __syncthreads();

    // 1) comp = sb @ w2 + CHUNK*b2
    #pragma unroll
    for (int u = 0; u < 4; ++u) {
        const int j = tid + u * 256;
        const int l = j >> 6, cc = j & 63;
        const float* sp = sb + l * H1;
        float a = (float)CHUNK * b2[cc];
        for (int k = 0; k < H1; ++k) a += sp[k] * wbuf[k * CDIM + cc];
        comp[j] = a;
    }
    __syncthreads();
    // 2) lnf over 1024
    {
        float s = 0.f, ss = 0.f;
        #pragma unroll
        for (int u = 0; u < 4; ++u) { const float v = comp[tid + u * 256]; s += v; ss += v * v; }
        red2[tid] = make_float2(s, ss);
        __syncthreads();
        for (int st = 128; st > 0; st >>= 1) {
            if (tid < st) {
                red2[tid].x += red2[tid + st].x;
                red2[tid].y += red2[tid + st].y;
            }
            __syncthreads();
        }
        if (tid == 0) {
            const float m = red2[0].x * (1.0f / 1024.0f);
            const float var = red2[0].y * (1.0f / 1024.0f) - m * m;
            mvS[0] = m; mvS[1] = rsqrtf(var + 1e-5f);
        }
        __syncthreads();
        const float m = mvS[0], r = mvS[1];
        #pragma unroll
        for (int u = 0; u < 4; ++u) {
            const int j = tid + u * 256;
            comp[j] = (comp[j] - m) * r * lnf_g[j] + lnf_b[j];
        }
    }
    __syncthreads();
    // 3) lnd per 64-wide row
    {
        const int l = tid >> 4, q = tid & 15;
        float s = 0.f, ss = 0.f;
        #pragma unroll
        for (int e = 0; e < 4; ++e) {
            const float v = comp[l * CDIM + q * 4 + e];
            s += v; ss += v * v;
        }
        red2[tid] = make_float2(s, ss);
        __syncthreads();
        if (tid < CLEN) {
            float sa = 0.f, sb2 = 0.f;
            for (int k = 0; k < 16; ++k) { sa += red2[tid * 16 + k].x; sb2 += red2[tid * 16 + k].y; }
            const float m = sa * (1.0f / 64.0f);
            const float var = sb2 * (1.0f / 64.0f) - m * m;
            m2S[tid] = m; r2S[tid] = rsqrtf(var + 1e-5f);
        }
        __syncthreads();
        #pragma unroll
        for (int u = 0; u < 4; ++u) {
            const int j = tid + u * 256;
            const int l2 = j >> 6, cc = j & 63;
            vv[l2][cc] = (comp[j] - m2S[l2]) * r2S[l2] * lnd_g[cc] + lnd_b[cc];
        }
    }
    __syncthreads();
    // stage dw1 (64x128) then hh = gelu(vv @ dw1 + db1)
    #pragma unroll
    for (int u = 0; u < 8; ++u) {
        const int j4 = (tid + u * 256) * 4;
        *(float4*)&wbuf[j4] = *(const float4*)(dw1 + j4);
    }
    __syncthreads();
    #pragma unroll
    for (int u = 0; u < 8; ++u) {
        const int j = tid + u * 256;
        const int l = j >> 7, cc = j & 127;
        float a = db1[cc];
        for (int k = 0; k < CDIM; ++k) a += vv[l][k] * wbuf[k * H1 + cc];
        hh[l][cc] = gelu_exact(a);
    }
    __syncthreads();
    // decRow = hh @ dw2 + db2, dw2 staged in four 64-col chunks (128x64 each)
    for (int ch = 0; ch < 4; ++ch) {
        const int c0 = ch * 64;
        #pragma unroll
        for (int u = 0; u < 8; ++u) {
            const int e = tid + u * 256;          // 0..2047
            const int k = e >> 4, cq = e & 15;    // k<128, 16 float4 per row
            *(float4*)&wbuf[k * 64 + cq * 4] =
                *(const float4*)(dw2 + (size_t)k * DD + c0 + cq * 4);
        }
        __syncthreads();
        #pragma unroll
        for (int u = 0; u < 4; ++u) {
            const int j = tid + u * 256;          // 0..1023
            const int l = j >> 6, cc = j & 63;
            float a = db2[c0 + cc];
            for (int k = 0; k < H1; ++k) a += hh[l][k] * wbuf[k * 64 + cc];
            decRow[(t * CLEN + l) * DD + c0 + cc] = a;
        }
        __syncthreads();
    }
}

// ---- Kernel 4: out[t,i,:] = decRow[t, idx[t,i]>>11, :] for i<8192 else 0 ----
__global__ __launch_bounds__(256) void k_gather(
    const int* __restrict__ indices, const float* __restrict__ decRow,
    float* __restrict__ out)
{
    const int tid = threadIdx.x;
    const int r = blockIdx.x * 4 + (tid >> 6);
    const int c4 = tid & 63;
    const int t = r / NTOK;
    const int i = r - t * NTOK;
    float4 v = make_float4(0.f, 0.f, 0.f, 0.f);
    if (i < NNODE) {
        const int node = indices[t * NNODE + i];
        const int l = node >> 11;
        v = *(const float4*)(decRow + (t * CLEN + l) * DD + c4 * 4);
    }
    *(float4*)(out + (size_t)r * DD + c4 * 4) = v;
}

extern "C" void kernel_launch(void* const* d_in, const int* in_sizes, int n_in,
                              void* d_out, int out_size, void* d_ws, size_t ws_size,
                              hipStream_t stream)
{
    const float* x       = (const float*)d_in[0];
    const int*   indices = (const int*)d_in[1];
    const float* ln1_g   = (const float*)d_in[2];
    const float* ln1_b   = (const float*)d_in[3];
    const float* w1      = (const float*)d_in[4];
    const float* b1      = (const float*)d_in[5];
    const float* w2      = (const float*)d_in[6];
    const float* b2      = (const float*)d_in[7];
    const float* lnf_g   = (const float*)d_in[8];
    const float* lnf_b   = (const float*)d_in[9];
    const float* lnd_g   = (const float*)d_in[10];
    const float* lnd_b   = (const float*)d_in[11];
    const float* dw1     = (const float*)d_in[12];
    const float* db1     = (const float*)d_in[13];
    const float* dw2     = (const float*)d_in[14];
    const float* db2     = (const float*)d_in[15];
    float* out = (float*)d_out;

    char* ws = (char*)d_ws;
    // zeroed region: cnt (1 MiB) + ovfcnt (32 B) + sbuf (64 KiB)
    int*   cnt    = (int*)ws;                            // 0x000000, 1 MiB
    int*   ovfcnt = (int*)(ws + 0x100000);               // 32 B
    float* sbuf   = (float*)(ws + 0x100020);             // 64 KiB -> ends 0x110020
    int*   slot0  = (int*)(ws + 0x120000);               // 1 MiB
    int*   slotsx = (int*)(ws + 0x220000);               // 15.75 MiB
    int*   ovf    = (int*)(ws + 0x11E0000);              // 256 KiB
    float* decRow = (float*)(ws + 0x1220000);            // 128 KiB
    float* y      = (float*)(ws + 0x1240000);            // 32 MiB

    hipMemsetAsync(ws, 0, 0x110020, stream);

    k_ln_gemm<<<dim3(128, 8), 256, 0, stream>>>(x, indices, ln1_g, ln1_b, w1, y,
                                                cnt, slot0, slotsx, ovfcnt, ovf);
    k_node_sum<<<dim3(8, 16, 8), 256, 0, stream>>>(y, b1, cnt, slot0, slotsx,
                                                   ovfcnt, ovf, sbuf);
    k_decode<<<8, 256, 0, stream>>>(sbuf, w2, b2, lnf_g, lnf_b, lnd_g, lnd_b,
                                    dw1, db1, dw2, db2, decRow);
    k_gather<<<24576, 256, 0, stream>>>(indices, decRow, out);
}